// Round 2
// baseline (279.389 us; speedup 1.0000x reference)
//
#include <hip/hip_runtime.h>
#include <math.h>

#define NBLOCKS 2048
#define BS 256
#define UNROLL 4

// Partials layout in d_ws (doubles):
// [0*NBLOCKS .. 1*NBLOCKS) : sum_all
// [1*NBLOCKS .. 2*NBLOCKS) : sum0 (y==0)
// [2*NBLOCKS .. 3*NBLOCKS) : cnt0 (as double, exact)
// [3*NBLOCKS .. 4*NBLOCKS) : min
// [4*NBLOCKS .. 5*NBLOCKS) : max

__global__ __launch_bounds__(BS, 4) void risk_pass1(const float* __restrict__ x,
                                                    const int* __restrict__ y,
                                                    double* __restrict__ ws,
                                                    int n4) {
    const float4* __restrict__ x4 = (const float4*)x;
    const int4*   __restrict__ y4 = (const int4*)y;

    const int stride = NBLOCKS * BS;
    const int tid = blockIdx.x * BS + threadIdx.x;

    // Independent accumulators per unroll slot to break dependency chains.
    double sacc[UNROLL]  = {0.0, 0.0, 0.0, 0.0};
    double s0acc[UNROLL] = {0.0, 0.0, 0.0, 0.0};
    int    cacc[UNROLL]  = {0, 0, 0, 0};
    float  mnacc[UNROLL] = { INFINITY,  INFINITY,  INFINITY,  INFINITY};
    float  mxacc[UNROLL] = {-INFINITY, -INFINITY, -INFINITY, -INFINITY};

    int i = tid;
    // Main unrolled loop: batch-issue all 8 loads, then consume.
    for (; i + (UNROLL - 1) * stride < n4; i += UNROLL * stride) {
        float4 xv[UNROLL];
        int4   yv[UNROLL];
        #pragma unroll
        for (int u = 0; u < UNROLL; ++u) {
            xv[u] = x4[i + u * stride];
            yv[u] = y4[i + u * stride];
        }
        #pragma unroll
        for (int u = 0; u < UNROLL; ++u) {
            float4 v = xv[u];
            int4   w = yv[u];
            // pairwise fp32 within the float4, promote once to double
            float s  = (v.x + v.y) + (v.z + v.w);
            float a  = (w.x == 0) ? v.x : 0.0f;
            float b  = (w.y == 0) ? v.y : 0.0f;
            float c  = (w.z == 0) ? v.z : 0.0f;
            float d  = (w.w == 0) ? v.w : 0.0f;
            float s0 = (a + b) + (c + d);
            sacc[u]  += (double)s;
            s0acc[u] += (double)s0;
            cacc[u]  += (w.x == 0) + (w.y == 0) + (w.z == 0) + (w.w == 0);
            mnacc[u] = fminf(mnacc[u], fminf(fminf(v.x, v.y), fminf(v.z, v.w)));
            mxacc[u] = fmaxf(mxacc[u], fmaxf(fmaxf(v.x, v.y), fmaxf(v.z, v.w)));
        }
    }
    // Tail (empty for N = 2^25, kept for generality)
    for (; i < n4; i += stride) {
        float4 v = x4[i];
        int4   w = y4[i];
        float s  = (v.x + v.y) + (v.z + v.w);
        float a  = (w.x == 0) ? v.x : 0.0f;
        float b  = (w.y == 0) ? v.y : 0.0f;
        float c  = (w.z == 0) ? v.z : 0.0f;
        float d  = (w.w == 0) ? v.w : 0.0f;
        sacc[0]  += (double)s;
        s0acc[0] += (double)((a + b) + (c + d));
        cacc[0]  += (w.x == 0) + (w.y == 0) + (w.z == 0) + (w.w == 0);
        mnacc[0] = fminf(mnacc[0], fminf(fminf(v.x, v.y), fminf(v.z, v.w)));
        mxacc[0] = fmaxf(mxacc[0], fmaxf(fmaxf(v.x, v.y), fmaxf(v.z, v.w)));
    }

    double sum  = (sacc[0]  + sacc[1])  + (sacc[2]  + sacc[3]);
    double sum0 = (s0acc[0] + s0acc[1]) + (s0acc[2] + s0acc[3]);
    int    cnt0 = (cacc[0] + cacc[1]) + (cacc[2] + cacc[3]);
    float  mn = fminf(fminf(mnacc[0], mnacc[1]), fminf(mnacc[2], mnacc[3]));
    float  mx = fmaxf(fmaxf(mxacc[0], mxacc[1]), fmaxf(mxacc[2], mxacc[3]));

    // wave (64-lane) reduction
    for (int off = 32; off > 0; off >>= 1) {
        sum  += __shfl_down(sum,  off);
        sum0 += __shfl_down(sum0, off);
        cnt0 += __shfl_down(cnt0, off);
        mn = fminf(mn, __shfl_down(mn, off));
        mx = fmaxf(mx, __shfl_down(mx, off));
    }

    __shared__ double s_sum[BS / 64], s_sum0[BS / 64];
    __shared__ int    s_cnt[BS / 64];
    __shared__ float  s_mn[BS / 64], s_mx[BS / 64];

    int lane = threadIdx.x & 63;
    int wave = threadIdx.x >> 6;
    if (lane == 0) {
        s_sum[wave] = sum; s_sum0[wave] = sum0; s_cnt[wave] = cnt0;
        s_mn[wave] = mn; s_mx[wave] = mx;
    }
    __syncthreads();

    if (threadIdx.x == 0) {
        double bsum = s_sum[0], bsum0 = s_sum0[0];
        int bcnt = s_cnt[0];
        float bmn = s_mn[0], bmx = s_mx[0];
        #pragma unroll
        for (int w = 1; w < BS / 64; ++w) {
            bsum += s_sum[w]; bsum0 += s_sum0[w]; bcnt += s_cnt[w];
            bmn = fminf(bmn, s_mn[w]); bmx = fmaxf(bmx, s_mx[w]);
        }
        ws[0 * NBLOCKS + blockIdx.x] = bsum;
        ws[1 * NBLOCKS + blockIdx.x] = bsum0;
        ws[2 * NBLOCKS + blockIdx.x] = (double)bcnt;
        ws[3 * NBLOCKS + blockIdx.x] = (double)bmn;
        ws[4 * NBLOCKS + blockIdx.x] = (double)bmx;
    }
}

__global__ __launch_bounds__(BS) void risk_pass2(const double* __restrict__ ws,
                                                 float* __restrict__ out,
                                                 long long n_total) {
    double sum = 0.0, sum0 = 0.0, cnt0 = 0.0;
    double mn =  INFINITY;
    double mx = -INFINITY;

    for (int i = threadIdx.x; i < NBLOCKS; i += BS) {
        sum  += ws[0 * NBLOCKS + i];
        sum0 += ws[1 * NBLOCKS + i];
        cnt0 += ws[2 * NBLOCKS + i];
        mn = fmin(mn, ws[3 * NBLOCKS + i]);
        mx = fmax(mx, ws[4 * NBLOCKS + i]);
    }

    for (int off = 32; off > 0; off >>= 1) {
        sum  += __shfl_down(sum,  off);
        sum0 += __shfl_down(sum0, off);
        cnt0 += __shfl_down(cnt0, off);
        mn = fmin(mn, __shfl_down(mn, off));
        mx = fmax(mx, __shfl_down(mx, off));
    }

    __shared__ double s_sum[BS / 64], s_sum0[BS / 64], s_cnt[BS / 64];
    __shared__ double s_mn[BS / 64], s_mx[BS / 64];
    int lane = threadIdx.x & 63;
    int wave = threadIdx.x >> 6;
    if (lane == 0) {
        s_sum[wave] = sum; s_sum0[wave] = sum0; s_cnt[wave] = cnt0;
        s_mn[wave] = mn; s_mx[wave] = mx;
    }
    __syncthreads();

    if (threadIdx.x == 0) {
        double tsum = s_sum[0], tsum0 = s_sum0[0], tcnt0 = s_cnt[0];
        double tmn = s_mn[0], tmx = s_mx[0];
        #pragma unroll
        for (int w = 1; w < BS / 64; ++w) {
            tsum += s_sum[w]; tsum0 += s_sum0[w]; tcnt0 += s_cnt[w];
            tmn = fmin(tmn, s_mn[w]); tmx = fmax(tmx, s_mx[w]);
        }
        double range = tmx - tmn;
        double n1 = (double)n_total - tcnt0;
        double sum1 = tsum - tsum0;
        double m0 = (tsum0 / tcnt0 - tmn) / range;
        double m1 = (sum1  / n1    - tmn) / range;
        double l = fmin(m0, m1) - fmax(m0, m1);  // = -|m0 - m1|
        out[0] = (float)l;
    }
}

extern "C" void kernel_launch(void* const* d_in, const int* in_sizes, int n_in,
                              void* d_out, int out_size, void* d_ws, size_t ws_size,
                              hipStream_t stream) {
    const float* x = (const float*)d_in[0];
    const int*   y = (const int*)d_in[1];
    float* out = (float*)d_out;
    double* ws = (double*)d_ws;
    long long n = (long long)in_sizes[0];
    int n4 = (int)(n / 4);  // N = 2^25, divisible by 4

    risk_pass1<<<NBLOCKS, BS, 0, stream>>>(x, y, ws, n4);
    risk_pass2<<<1, BS, 0, stream>>>(ws, out, n);
}

// Round 3
// 276.898 us; speedup vs baseline: 1.0090x; 1.0090x over previous
//
#include <hip/hip_runtime.h>
#include <math.h>

#define NBLOCKS 8192
#define BS 256
#define K 4          // float4s per thread; NBLOCKS*BS*K == N/4 == 2^23
#define P2BS 1024    // pass2 block size

// Partials layout in d_ws (doubles):
// [0*NBLOCKS .. 1*NBLOCKS) : sum_all
// [1*NBLOCKS .. 2*NBLOCKS) : sum0 (y==0)
// [2*NBLOCKS .. 3*NBLOCKS) : cnt0 (as double, exact)
// [3*NBLOCKS .. 4*NBLOCKS) : min
// [4*NBLOCKS .. 5*NBLOCKS) : max

__device__ __forceinline__ void consume(const float4 v, const int4 w,
                                        float& s, float& s0, int& c,
                                        float& mn, float& mx) {
    s  = (v.x + v.y) + (v.z + v.w);
    float a = (w.x == 0) ? v.x : 0.0f;
    float b = (w.y == 0) ? v.y : 0.0f;
    float cc = (w.z == 0) ? v.z : 0.0f;
    float d = (w.w == 0) ? v.w : 0.0f;
    s0 = (a + b) + (cc + d);
    c  = (w.x == 0) + (w.y == 0) + (w.z == 0) + (w.w == 0);
    mn = fminf(fminf(v.x, v.y), fminf(v.z, v.w));
    mx = fmaxf(fmaxf(v.x, v.y), fmaxf(v.z, v.w));
}

__global__ __launch_bounds__(BS) void risk_pass1(const float* __restrict__ x,
                                                 const int* __restrict__ y,
                                                 double* __restrict__ ws) {
    const float4* __restrict__ x4 = (const float4*)x;
    const int4*   __restrict__ y4 = (const int4*)y;

    // Block-contiguous: block b owns float4 range [b*BS*K, (b+1)*BS*K).
    const int base = blockIdx.x * (BS * K) + threadIdx.x;

    // Issue all 8 loads up-front as independent named values.
    float4 xv0 = x4[base + 0 * BS];
    float4 xv1 = x4[base + 1 * BS];
    float4 xv2 = x4[base + 2 * BS];
    float4 xv3 = x4[base + 3 * BS];
    int4   yv0 = y4[base + 0 * BS];
    int4   yv1 = y4[base + 1 * BS];
    int4   yv2 = y4[base + 2 * BS];
    int4   yv3 = y4[base + 3 * BS];

    float s0f, s1f, s2f, s3f;          // per-chunk fp32 sums
    float t0, t1, t2, t3;              // per-chunk fp32 label-0 sums
    int   c0, c1, c2, c3;
    float mn0, mn1, mn2, mn3, mx0, mx1, mx2, mx3;

    consume(xv0, yv0, s0f, t0, c0, mn0, mx0);
    consume(xv1, yv1, s1f, t1, c1, mn1, mx1);
    consume(xv2, yv2, s2f, t2, c2, mn2, mx2);
    consume(xv3, yv3, s3f, t3, c3, mn3, mx3);

    // promote to double once per thread (pairwise)
    double sum  = ((double)s0f + (double)s1f) + ((double)s2f + (double)s3f);
    double sum0 = ((double)t0 + (double)t1) + ((double)t2 + (double)t3);
    int    cnt0 = (c0 + c1) + (c2 + c3);
    float  mn = fminf(fminf(mn0, mn1), fminf(mn2, mn3));
    float  mx = fmaxf(fmaxf(mx0, mx1), fmaxf(mx2, mx3));

    // wave (64-lane) reduction
    for (int off = 32; off > 0; off >>= 1) {
        sum  += __shfl_down(sum,  off);
        sum0 += __shfl_down(sum0, off);
        cnt0 += __shfl_down(cnt0, off);
        mn = fminf(mn, __shfl_down(mn, off));
        mx = fmaxf(mx, __shfl_down(mx, off));
    }

    __shared__ double s_sum[BS / 64], s_sum0[BS / 64];
    __shared__ int    s_cnt[BS / 64];
    __shared__ float  s_mn[BS / 64], s_mx[BS / 64];

    int lane = threadIdx.x & 63;
    int wave = threadIdx.x >> 6;
    if (lane == 0) {
        s_sum[wave] = sum; s_sum0[wave] = sum0; s_cnt[wave] = cnt0;
        s_mn[wave] = mn; s_mx[wave] = mx;
    }
    __syncthreads();

    if (threadIdx.x == 0) {
        double bsum = s_sum[0], bsum0 = s_sum0[0];
        int bcnt = s_cnt[0];
        float bmn = s_mn[0], bmx = s_mx[0];
        #pragma unroll
        for (int w = 1; w < BS / 64; ++w) {
            bsum += s_sum[w]; bsum0 += s_sum0[w]; bcnt += s_cnt[w];
            bmn = fminf(bmn, s_mn[w]); bmx = fmaxf(bmx, s_mx[w]);
        }
        ws[0 * NBLOCKS + blockIdx.x] = bsum;
        ws[1 * NBLOCKS + blockIdx.x] = bsum0;
        ws[2 * NBLOCKS + blockIdx.x] = (double)bcnt;
        ws[3 * NBLOCKS + blockIdx.x] = (double)bmn;
        ws[4 * NBLOCKS + blockIdx.x] = (double)bmx;
    }
}

__global__ __launch_bounds__(P2BS) void risk_pass2(const double* __restrict__ ws,
                                                   float* __restrict__ out,
                                                   long long n_total) {
    double sum = 0.0, sum0 = 0.0, cnt0 = 0.0;
    double mn =  INFINITY;
    double mx = -INFINITY;

    for (int i = threadIdx.x; i < NBLOCKS; i += P2BS) {
        sum  += ws[0 * NBLOCKS + i];
        sum0 += ws[1 * NBLOCKS + i];
        cnt0 += ws[2 * NBLOCKS + i];
        mn = fmin(mn, ws[3 * NBLOCKS + i]);
        mx = fmax(mx, ws[4 * NBLOCKS + i]);
    }

    for (int off = 32; off > 0; off >>= 1) {
        sum  += __shfl_down(sum,  off);
        sum0 += __shfl_down(sum0, off);
        cnt0 += __shfl_down(cnt0, off);
        mn = fmin(mn, __shfl_down(mn, off));
        mx = fmax(mx, __shfl_down(mx, off));
    }

    __shared__ double s_sum[P2BS / 64], s_sum0[P2BS / 64], s_cnt[P2BS / 64];
    __shared__ double s_mn[P2BS / 64], s_mx[P2BS / 64];
    int lane = threadIdx.x & 63;
    int wave = threadIdx.x >> 6;
    if (lane == 0) {
        s_sum[wave] = sum; s_sum0[wave] = sum0; s_cnt[wave] = cnt0;
        s_mn[wave] = mn; s_mx[wave] = mx;
    }
    __syncthreads();

    if (threadIdx.x == 0) {
        double tsum = s_sum[0], tsum0 = s_sum0[0], tcnt0 = s_cnt[0];
        double tmn = s_mn[0], tmx = s_mx[0];
        #pragma unroll
        for (int w = 1; w < P2BS / 64; ++w) {
            tsum += s_sum[w]; tsum0 += s_sum0[w]; tcnt0 += s_cnt[w];
            tmn = fmin(tmn, s_mn[w]); tmx = fmax(tmx, s_mx[w]);
        }
        double range = tmx - tmn;
        double n1 = (double)n_total - tcnt0;
        double sum1 = tsum - tsum0;
        double m0 = (tsum0 / tcnt0 - tmn) / range;
        double m1 = (sum1  / n1    - tmn) / range;
        double l = fmin(m0, m1) - fmax(m0, m1);  // = -|m0 - m1|
        out[0] = (float)l;
    }
}

extern "C" void kernel_launch(void* const* d_in, const int* in_sizes, int n_in,
                              void* d_out, int out_size, void* d_ws, size_t ws_size,
                              hipStream_t stream) {
    const float* x = (const float*)d_in[0];
    const int*   y = (const int*)d_in[1];
    float* out = (float*)d_out;
    double* ws = (double*)d_ws;
    long long n = (long long)in_sizes[0];  // 33554432 = NBLOCKS*BS*K*4 exactly

    risk_pass1<<<NBLOCKS, BS, 0, stream>>>(x, y, ws);
    risk_pass2<<<1, P2BS, 0, stream>>>(ws, out, n);
}